// Round 7
// baseline (162.739 us; speedup 1.0000x reference)
//
#include <hip/hip_runtime.h>
#include <math.h>

#define NN 512
#define FF 64
#define HH 64
#define CC 32
#define KK 50

typedef unsigned int uint;
typedef short bhalf8_t __attribute__((ext_vector_type(8)));
typedef float f32x4_t __attribute__((ext_vector_type(4)));
#define MFMA16 __builtin_amdgcn_mfma_f32_16x16x32_bf16

union FragA { bhalf8_t v; uint u[4]; short4 h[2]; };

__device__ __forceinline__ float frcp(float x){ return __builtin_amdgcn_rcpf(x); }
__device__ __forceinline__ float fsilu(float x){ return x * frcp(1.0f + __expf(-x)); }
__device__ __forceinline__ float ftanh(float x){ return 1.0f - 2.0f * frcp(__expf(2.0f*x) + 1.0f); }
__device__ __forceinline__ short f2bf(float f){            // RNE f32->bf16
    uint u = __float_as_uint(f);
    return (short)((u + 0x7FFFu + ((u >> 16) & 1u)) >> 16);
}
__device__ __forceinline__ uint pack2(float lo, float hi){
    return (uint)(unsigned short)f2bf(lo) | ((uint)(unsigned short)f2bf(hi) << 16);
}

__device__ __forceinline__ float bfly_max(float v){
    #pragma unroll
    for (int m = 1; m < 64; m <<= 1) v = fmaxf(v, __shfl_xor(v, m, 64));
    return v;
}
__device__ __forceinline__ float bfly_sum(float v){
    #pragma unroll
    for (int m = 1; m < 64; m <<= 1) v += __shfl_xor(v, m, 64);
    return v;
}
__device__ __forceinline__ float block_max4(float v, float* red, int lane, int wid){
    v = bfly_max(v);
    __syncthreads();
    if (lane == 0) red[wid] = v;
    __syncthreads();
    return fmaxf(fmaxf(red[0], red[1]), fmaxf(red[2], red[3]));
}
__device__ __forceinline__ float block_sum4(float v, float* red, int lane, int wid){
    v = bfly_sum(v);
    __syncthreads();
    if (lane == 0) red[wid] = v;
    __syncthreads();
    return (red[0] + red[1]) + (red[2] + red[3]);
}

// ---------------- kernel 1: per-node projections + weight fragments ----------------
extern "C" __global__ __launch_bounds__(128)
void sake_pre(const float* __restrict__ h,
              const float* __restrict__ W_df_in, const float* __restrict__ b_df_in,
              const float* __restrict__ W_ew,    const float* __restrict__ b_ew,
              const float* __restrict__ W_sa,
              const float* __restrict__ W_df1, const float* __restrict__ W_df2,
              const float* __restrict__ W_cm1,
              float* __restrict__ Am, float* __restrict__ Cm,
              float* __restrict__ Em, float* __restrict__ Fm,
              float* __restrict__ sa, float* __restrict__ sb,
              short* __restrict__ Wf1, short* __restrict__ Wf2,
              short* __restrict__ Wfc, short* __restrict__ Wfe)
{
    const int b = blockIdx.x;
    const int t = threadIdx.x;
    if (b < NN) {
        __shared__ float hrow[FF];
        if (t < FF) hrow[t] = h[b*FF + t];
        __syncthreads();
        if (t < 64) {
            if (t < KK) {
                float a_ = 0.f, c_ = b_df_in[t];
                #pragma unroll 8
                for (int f = 0; f < FF; ++f) {
                    a_ += hrow[f] * W_df_in[f*KK + t];
                    c_ += hrow[f] * W_df_in[(FF+f)*KK + t];
                }
                Am[b*64 + t] = a_;   // [j][k] fp32, k-padded
                Cm[b*64 + t] = c_;   // [i][k], bias folded
            } else {
                Am[b*64 + t] = 0.f;  // zero-pad k=50..63 (makes he0 pad exact 0)
                Cm[b*64 + t] = 0.f;
            }
        } else if (t < 96) {
            int cc = t - 64;
            float e = 0.f, ff2 = b_ew[cc];
            #pragma unroll 8
            for (int f = 0; f < FF; ++f) {
                e   += hrow[f] * W_ew[f*CC + cc];
                ff2 += hrow[f] * W_ew[(FF+f)*CC + cc];
            }
            Em[b*CC + cc] = e;       // [j][c]
            Fm[b*CC + cc] = ff2;     // [i][c], b_ew folded
        } else if (t == 96) {
            float v = 0.f;
            #pragma unroll 8
            for (int f = 0; f < FF; ++f) v += hrow[f] * W_sa[f];
            sa[b] = v;
        } else if (t == 97) {
            float v = 0.f;
            #pragma unroll 8
            for (int f = 0; f < FF; ++f) v += hrow[f] * W_sa[FF + f];
            sb[b] = v;
        }
    } else {
        // weight -> bf16 MFMA-B-fragment order: idx = ((nt*2+ks)*64 + lane)*8 + q
        // value = W[k = 32*ks + 8*(lane>>4) + q][n = 16*nt + (lane&15)]
        const int wb = b - NN;
        const int cnt = (wb == 3) ? 2048 : 4096;
        #pragma unroll 4
        for (int idx = t; idx < cnt; idx += 128) {
            int q  = idx & 7;
            int l  = (idx >> 3) & 63;
            int ks = (idx >> 9) & 1;
            int nt = idx >> 10;
            int k  = 32*ks + 8*(l >> 4) + q;
            int n  = 16*nt + (l & 15);
            float v;
            if (wb == 0)      v = (k < KK) ? W_df1[k*HH + n] : 0.f;  // [50][64], pad rows 0
            else if (wb == 1) v = W_df2[k*HH + n];                    // [64][64]
            else if (wb == 2) v = W_cm1[k*HH + n];                    // [64][64]
            else              v = W_ew[(128 + k)*CC + n];             // he-rows of [192][32]
            short* dst = (wb == 0) ? Wf1 : (wb == 1) ? Wf2 : (wb == 2) ? Wfc : Wfe;
            dst[idx] = f2bf(v);
        }
    }
}

// ---------------- kernel 2: fused per-row-i MFMA main kernel ----------------
// 256 threads (4 waves), 8 j-tiles/wave. B-fragments read DIRECTLY from global
// (L1/L2-hot, identical stream for all blocks) -- no LDS weight staging.
// LDS ~26.5KB => >=4 blocks/CU by LDS; all 512 blocks co-resident (kills the
// round-6 2-sequential-rounds tail, OccupancyPercent 20%).
#define OFF_TILE 0        // 4 waves * 16*76 shorts = 9728B
#define OFF_DIST 9728     // 512 f32
#define OFF_DX   11776    // 512*3 f32
#define OFF_ATTW 17920    // 512 f32
#define OFF_CORD 19968    // 512 f32
#define OFF_SCM  22016    // 64 f32
#define OFF_SB1  22272
#define OFF_SB2  22528
#define OFF_SBC1 22784
#define OFF_WC2  23040
#define OFF_FM   23296    // 32 f32
#define OFF_BC2  23424
#define SMEM_BYTES 23552

extern "C" __global__ __launch_bounds__(256)
void sake_main(const float* __restrict__ x,
               const float* __restrict__ b_df1, const float* __restrict__ b_df2,
               const float* __restrict__ b_cm1,
               const float* __restrict__ W_cm2, const float* __restrict__ b_cm2,
               const float* __restrict__ Am, const float* __restrict__ Cm,
               const float* __restrict__ Em, const float* __restrict__ Fm,
               const float* __restrict__ sa, const float* __restrict__ sb,
               const short* __restrict__ Wf1, const short* __restrict__ Wf2,
               const short* __restrict__ Wfc, const short* __restrict__ Wfe,
               float* __restrict__ heagg, float* __restrict__ xan,
               float* __restrict__ out)
{
    extern __shared__ char smem[];
    float* dist_s = (float*)(smem + OFF_DIST);
    float* dx_s   = (float*)(smem + OFF_DX);
    float* attw_s = (float*)(smem + OFF_ATTW);
    float* cord_s = (float*)(smem + OFF_CORD);
    float* sCm    = (float*)(smem + OFF_SCM);
    float* sB1    = (float*)(smem + OFF_SB1);
    float* sB2    = (float*)(smem + OFF_SB2);
    float* sBc1   = (float*)(smem + OFF_SBC1);
    float* sWc2   = (float*)(smem + OFF_WC2);
    float* sFm    = (float*)(smem + OFF_FM);
    float* sBc2   = (float*)(smem + OFF_BC2);

    __shared__ float red[4];
    __shared__ float sAggH[4][64];
    __shared__ float sAccX[4][96];
    __shared__ float xatt_f[96];

    const int i   = blockIdx.x;
    const int tid = threadIdx.x;
    const int lane = tid & 63, wid = tid >> 6;

    // ---- stage row-i constants into LDS (no weight staging) ----
    if (tid < 64) {
        sCm[tid]  = Cm[i*64 + tid];
        sB1[tid]  = b_df1[tid];
        sB2[tid]  = b_df2[tid];
        sBc1[tid] = b_cm1[tid];
        sWc2[tid] = W_cm2[tid];
    }
    if (tid < 32) sFm[tid] = Fm[i*CC + tid];
    if (tid == 0) sBc2[0] = b_cm2[0];

    // ---- phase A: softmax normalizers (2 j per thread) ----
    const float xi0 = x[i*3+0], xi1 = x[i*3+1], xi2 = x[i*3+2];
    const float sbi = sb[i];
    {
        float dj[2], sv[2];
        #pragma unroll
        for (int u = 0; u < 2; ++u) {
            const int j = tid + u*256;
            float d0 = x[j*3+0]-xi0, d1 = x[j*3+1]-xi1, d2c = x[j*3+2]-xi2;
            float d2 = d0*d0 + d1*d1 + d2c*d2c;
            dj[u] = sqrtf(d2 + 1e-14f);
            sv[u] = fsilu(sa[j] + sbi);
            dist_s[j] = dj[u];
            dx_s[j*3+0] = d0; dx_s[j*3+1] = d1; dx_s[j*3+2] = d2c;
        }
        float dmax = block_max4(fmaxf(dj[0], dj[1]), red, lane, wid);
        float dsum = block_sum4(__expf(dj[0]-dmax) + __expf(dj[1]-dmax), red, lane, wid);
        float smax = block_max4(fmaxf(sv[0], sv[1]), red, lane, wid);
        float ssum = block_sum4(__expf(sv[0]-smax) + __expf(sv[1]-smax), red, lane, wid);
        float inv_ds = frcp(dsum * ssum);
        float p0 = __expf((dj[0]-dmax) + (sv[0]-smax)) * inv_ds;
        float p1 = __expf((dj[1]-dmax) + (sv[1]-smax)) * inv_ds;
        float pmax = block_max4(fmaxf(p0, p1), red, lane, wid);
        float t0 = __expf(p0 - pmax), t1 = __expf(p1 - pmax);
        float tsum = block_sum4(t0 + t1, red, lane, wid);
        float inv_tsum = frcp(tsum);
        attw_s[tid]       = t0 * inv_tsum;
        attw_s[tid + 256] = t1 * inv_tsum;
    }
    __syncthreads();

    // ---- phase B: MFMA chain, 4 waves x 8 M-tiles of 16 j ----
    const int w = wid, l = lane, a = l & 15, g = l >> 4;
    const float gf = (float)(8 * g);
    short* myTile = (short*)(smem + OFF_TILE) + w * (16 * 76);
    const float4* Amv  = (const float4*)Am;
    const float4* sCmv = (const float4*)sCm;
    const bhalf8_t* pW1 = (const bhalf8_t*)Wf1;
    const bhalf8_t* pW2 = (const bhalf8_t*)Wf2;
    const bhalf8_t* pWc = (const bhalf8_t*)Wfc;
    const bhalf8_t* pWe = (const bhalf8_t*)Wfe;

    float b1n[4], b2n[4], bcn[4], wc2r[4];
    #pragma unroll
    for (int nt = 0; nt < 4; ++nt) {
        b1n[nt]  = sB1[16*nt + a];
        b2n[nt]  = sB2[16*nt + a];
        bcn[nt]  = sBc1[16*nt + a];
        wc2r[nt] = sWc2[16*nt + a];
    }
    float fmr0 = sFm[a], fmr1 = sFm[16 + a];
    const float bc2v = sBc2[0];

    float aggH[4] = {0.f, 0.f, 0.f, 0.f};
    float xAcc[6] = {0.f, 0.f, 0.f, 0.f, 0.f, 0.f};

    const float MUK  = 5.0f / 49.0f;
    const float RBFC = -14.4269504f;   // -10 * log2(e)

    #pragma unroll 1
    for (int t = 0; t < 8; ++t) {
        const int Mb   = (w*8 + t)*16;
        const int jrow = Mb + a;         // A-row this lane builds/reads
        const int jred = Mb + 4*g;       // D-row base (add r)
        const float dj = dist_s[jrow];

        // ---- build he0 A-fragments (k = 32s + 8g + q), pad exact-0 ----
        FragA a0, a1;
        #pragma unroll
        for (int s = 0; s < 2; ++s) {
            float4 amL = Amv[jrow*16 + s*8 + g*2];
            float4 amH = Amv[jrow*16 + s*8 + g*2 + 1];
            float4 cmL = sCmv[s*8 + g*2];
            float4 cmH = sCmv[s*8 + g*2 + 1];
            float vq[8];
            vq[0] = amL.x + cmL.x; vq[1] = amL.y + cmL.y;
            vq[2] = amL.z + cmL.z; vq[3] = amL.w + cmL.w;
            vq[4] = amH.x + cmH.x; vq[5] = amH.y + cmH.y;
            vq[6] = amH.z + cmH.z; vq[7] = amH.w + cmH.w;
            #pragma unroll
            for (int q = 0; q < 8; ++q) {
                float kf = gf + (float)(32*s + q);
                float dd = dj - kf * MUK;
                vq[q] *= exp2f(dd * dd * RBFC);
            }
            FragA* ap = s ? &a1 : &a0;
            ap->u[0] = pack2(vq[0], vq[1]);
            ap->u[1] = pack2(vq[2], vq[3]);
            ap->u[2] = pack2(vq[4], vq[5]);
            ap->u[3] = pack2(vq[6], vq[7]);
        }

        // ---- stage 1: he1 = silu(he0 @ W_df1 + b1) ----
        f32x4_t acc[4];
        #pragma unroll
        for (int nt = 0; nt < 4; ++nt) acc[nt] = (f32x4_t){b1n[nt], b1n[nt], b1n[nt], b1n[nt]};
        #pragma unroll
        for (int s = 0; s < 2; ++s) {
            bhalf8_t av = s ? a1.v : a0.v;
            #pragma unroll
            for (int nt = 0; nt < 4; ++nt) {
                bhalf8_t bv = pW1[(nt*2 + s)*64 + l];
                acc[nt] = MFMA16(av, bv, acc[nt], 0, 0, 0);
            }
        }
        #pragma unroll
        for (int nt = 0; nt < 4; ++nt) {
            #pragma unroll
            for (int r = 0; r < 4; ++r)
                myTile[(4*g + r)*76 + a + 16*nt] = f2bf(fsilu(acc[nt][r]));
        }

        // ---- stage 2: he = he1 @ W_df2 + b2 ----
        FragA h0, h1;
        h0.h[0] = *(const short4*)&myTile[a*76 + 8*g];
        h0.h[1] = *(const short4*)&myTile[a*76 + 8*g + 4];
        h1.h[0] = *(const short4*)&myTile[a*76 + 32 + 8*g];
        h1.h[1] = *(const short4*)&myTile[a*76 + 32 + 8*g + 4];
        #pragma unroll
        for (int nt = 0; nt < 4; ++nt) acc[nt] = (f32x4_t){b2n[nt], b2n[nt], b2n[nt], b2n[nt]};
        #pragma unroll
        for (int s = 0; s < 2; ++s) {
            bhalf8_t av = s ? h1.v : h0.v;
            #pragma unroll
            for (int nt = 0; nt < 4; ++nt) {
                bhalf8_t bv = pW2[(nt*2 + s)*64 + l];
                acc[nt] = MFMA16(av, bv, acc[nt], 0, 0, 0);
            }
        }
        // he_agg partial (total_att * he) straight from D regs
        float at0 = attw_s[jred+0], at1 = attw_s[jred+1],
              at2 = attw_s[jred+2], at3 = attw_s[jred+3];
        #pragma unroll
        for (int nt = 0; nt < 4; ++nt) {
            aggH[nt] += at0*acc[nt][0] + at1*acc[nt][1] + at2*acc[nt][2] + at3*acc[nt][3];
            #pragma unroll
            for (int r = 0; r < 4; ++r)
                myTile[(4*g + r)*76 + a + 16*nt] = f2bf(acc[nt][r]);   // he -> tile
        }

        // re-read he as A-fragments (shared by edge & cm1 stages)
        FragA e0, e1;
        e0.h[0] = *(const short4*)&myTile[a*76 + 8*g];
        e0.h[1] = *(const short4*)&myTile[a*76 + 8*g + 4];
        e1.h[0] = *(const short4*)&myTile[a*76 + 32 + 8*g];
        e1.h[1] = *(const short4*)&myTile[a*76 + 32 + 8*g + 4];

        // ---- edge: w_edge = tanh(E_j + F_i + he @ W_ew_he), fused x_att reduce ----
        f32x4_t ae[2];
        ae[0] = (f32x4_t){0.f,0.f,0.f,0.f};
        ae[1] = (f32x4_t){0.f,0.f,0.f,0.f};
        #pragma unroll
        for (int s = 0; s < 2; ++s) {
            bhalf8_t av = s ? e1.v : e0.v;
            #pragma unroll
            for (int nt = 0; nt < 2; ++nt) {
                bhalf8_t bv = pWe[(nt*2 + s)*64 + l];
                ae[nt] = MFMA16(av, bv, ae[nt], 0, 0, 0);
            }
        }
        float xd[4][3];
        #pragma unroll
        for (int r = 0; r < 4; ++r) {
            float dr = dist_s[jred + r];
            float iv = frcp(dr*dr + 1e-5f);
            xd[r][0] = dx_s[(jred+r)*3+0] * iv;
            xd[r][1] = dx_s[(jred+r)*3+1] * iv;
            xd[r][2] = dx_s[(jred+r)*3+2] * iv;
        }
        #pragma unroll
        for (int nt = 0; nt < 2; ++nt) {
            float fmv = nt ? fmr1 : fmr0;
            #pragma unroll
            for (int r = 0; r < 4; ++r) {
                float em = Em[(jred+r)*CC + a + 16*nt];
                float wv = ftanh(ae[nt][r] + em + fmv);
                xAcc[nt*3+0] += wv * xd[r][0];
                xAcc[nt*3+1] += wv * xd[r][1];
                xAcc[nt*3+2] += wv * xd[r][2];
            }
        }

        // ---- coord MLP: coordw = silu(he @ W_cm1 + bc1) @ W_cm2 + bc2 ----
        #pragma unroll
        for (int nt = 0; nt < 4; ++nt) acc[nt] = (f32x4_t){bcn[nt], bcn[nt], bcn[nt], bcn[nt]};
        #pragma unroll
        for (int s = 0; s < 2; ++s) {
            bhalf8_t av = s ? e1.v : e0.v;
            #pragma unroll
            for (int nt = 0; nt < 4; ++nt) {
                bhalf8_t bv = pWc[(nt*2 + s)*64 + l];
                acc[nt] = MFMA16(av, bv, acc[nt], 0, 0, 0);
            }
        }
        float cw[4] = {0.f, 0.f, 0.f, 0.f};
        #pragma unroll
        for (int nt = 0; nt < 4; ++nt) {
            #pragma unroll
            for (int r = 0; r < 4; ++r)
                cw[r] += fsilu(acc[nt][r]) * wc2r[nt];
        }
        #pragma unroll
        for (int m = 1; m < 16; m <<= 1) {
            #pragma unroll
            for (int r = 0; r < 4; ++r) cw[r] += __shfl_xor(cw[r], m, 64);
        }
        if (a == 0) {
            #pragma unroll
            for (int r = 0; r < 4; ++r) cord_s[jred + r] = cw[r] + bc2v;
        }
    }

    // ---- wave-level combine of j-reductions ----
    #pragma unroll
    for (int nt = 0; nt < 4; ++nt) {
        aggH[nt] += __shfl_xor(aggH[nt], 16, 64);
        aggH[nt] += __shfl_xor(aggH[nt], 32, 64);
    }
    #pragma unroll
    for (int q = 0; q < 6; ++q) {
        xAcc[q] += __shfl_xor(xAcc[q], 16, 64);
        xAcc[q] += __shfl_xor(xAcc[q], 32, 64);
    }
    if (l < 16) {
        #pragma unroll
        for (int nt = 0; nt < 4; ++nt) sAggH[w][l + 16*nt] = aggH[nt];
        #pragma unroll
        for (int d = 0; d < 3; ++d) {
            sAccX[w][l*3 + d]        = xAcc[d];
            sAccX[w][(l+16)*3 + d]   = xAcc[3 + d];
        }
    }
    __syncthreads();

    // ---- x_new = sum_j dx * coordw + x_i (2 j per thread) ----
    {
        float cw0 = cord_s[tid], cw1 = cord_s[tid + 256];
        float X0 = block_sum4(dx_s[tid*3+0]*cw0 + dx_s[(tid+256)*3+0]*cw1, red, lane, wid);
        float X1 = block_sum4(dx_s[tid*3+1]*cw0 + dx_s[(tid+256)*3+1]*cw1, red, lane, wid);
        float X2 = block_sum4(dx_s[tid*3+2]*cw0 + dx_s[(tid+256)*3+2]*cw1, red, lane, wid);
        if (tid == 0) {
            out[NN*HH + i*3+0] = X0 + xi0;
            out[NN*HH + i*3+1] = X1 + xi1;
            out[NN*HH + i*3+2] = X2 + xi2;
        }
    }

    // ---- cross-wave combine: store he_agg and xan to workspace ----
    if (tid < 64) {
        float s = 0.f;
        #pragma unroll
        for (int ww = 0; ww < 4; ++ww) s += sAggH[ww][tid];
        heagg[i*64 + tid] = s;
    }
    if (tid < 96) {
        float s = 0.f;
        #pragma unroll
        for (int ww = 0; ww < 4; ++ww) s += sAccX[ww][tid];
        xatt_f[tid] = s;
    }
    __syncthreads();
    if (tid < 32) {
        float aa = xatt_f[tid*3+0], bb = xatt_f[tid*3+1], cc = xatt_f[tid*3+2];
        xan[i*32 + tid] = sqrtf(aa*aa + bb*bb + cc*cc + 1e-14f);
    }
}

// ---------------- kernel 3: per-node epilogue MLPs (node-parallel) ----------------
extern "C" __global__ __launch_bounds__(64)
void sake_post(const float* __restrict__ h,
               const float* __restrict__ W_pn1, const float* __restrict__ b_pn1,
               const float* __restrict__ W_pn2, const float* __restrict__ b_pn2,
               const float* __restrict__ W_nm1, const float* __restrict__ b_nm1,
               const float* __restrict__ W_nm2, const float* __restrict__ b_nm2,
               const float* __restrict__ heagg, const float* __restrict__ xan,
               float* __restrict__ out)
{
    const int i = blockIdx.x;
    const int n = threadIdx.x;
    __shared__ float pn1_s[64];
    __shared__ float node_in[192];
    __shared__ float nm1_s[64];

    float acc = b_pn1[n];
    #pragma unroll
    for (int c = 0; c < CC; ++c) acc += xan[i*CC + c] * W_pn1[c*HH + n];
    pn1_s[n] = fsilu(acc);
    __syncthreads();

    acc = b_pn2[n];
    #pragma unroll 16
    for (int k = 0; k < HH; ++k) acc += pn1_s[k] * W_pn2[k*HH + n];
    node_in[128 + n] = acc;              // norm_emb
    node_in[n]       = h[i*FF + n];      // h
    node_in[64 + n]  = heagg[i*64 + n];  // he_agg
    __syncthreads();

    acc = b_nm1[n];
    #pragma unroll 16
    for (int k = 0; k < 192; ++k) acc += node_in[k] * W_nm1[k*HH + n];
    nm1_s[n] = fsilu(acc);
    __syncthreads();

    acc = b_nm2[n];
    #pragma unroll 16
    for (int k = 0; k < HH; ++k) acc += nm1_s[k] * W_nm2[k*HH + n];
    out[i*HH + n] = acc;                 // h_new
}

extern "C" void kernel_launch(void* const* d_in, const int* in_sizes, int n_in,
                              void* d_out, int out_size, void* d_ws, size_t ws_size,
                              hipStream_t stream)
{
    const float* h       = (const float*)d_in[0];
    const float* x       = (const float*)d_in[1];
    const float* W_df_in = (const float*)d_in[2];
    const float* b_df_in = (const float*)d_in[3];
    const float* W_df1   = (const float*)d_in[4];
    const float* b_df1   = (const float*)d_in[5];
    const float* W_df2   = (const float*)d_in[6];
    const float* b_df2   = (const float*)d_in[7];
    const float* W_ew    = (const float*)d_in[8];
    const float* b_ew    = (const float*)d_in[9];
    const float* W_pn1   = (const float*)d_in[10];
    const float* b_pn1   = (const float*)d_in[11];
    const float* W_pn2   = (const float*)d_in[12];
    const float* b_pn2   = (const float*)d_in[13];
    const float* W_nm1   = (const float*)d_in[14];
    const float* b_nm1   = (const float*)d_in[15];
    const float* W_nm2   = (const float*)d_in[16];
    const float* b_nm2   = (const float*)d_in[17];
    const float* W_cm1   = (const float*)d_in[18];
    const float* b_cm1   = (const float*)d_in[19];
    const float* W_cm2   = (const float*)d_in[20];
    const float* b_cm2   = (const float*)d_in[21];
    const float* W_sa    = (const float*)d_in[22];
    float* out = (float*)d_out;

    float* ws = (float*)d_ws;
    float* Am = ws;                   // 512*64
    float* Cm = Am + 512*64;          // 512*64
    float* Em = Cm + 512*64;          // 512*32
    float* Fm = Em + 512*32;          // 512*32
    float* sa = Fm + 512*32;          // 512
    float* sb = sa + 512;             // 512
    short* Wf1 = (short*)(sb + 512);  // 4096 shorts
    short* Wf2 = Wf1 + 4096;
    short* Wfc = Wf2 + 4096;
    short* Wfe = Wfc + 4096;          // 2048 shorts
    float* heagg = (float*)(Wfe + 2048);  // 512*64
    float* xan   = heagg + 512*64;        // 512*32

    (void)hipFuncSetAttribute((const void*)sake_main,
        hipFuncAttributeMaxDynamicSharedMemorySize, SMEM_BYTES);

    sake_pre<<<NN + 4, 128, 0, stream>>>(h, W_df_in, b_df_in, W_ew, b_ew, W_sa,
                                         W_df1, W_df2, W_cm1,
                                         Am, Cm, Em, Fm, sa, sb,
                                         Wf1, Wf2, Wfc, Wfe);
    sake_main<<<NN, 256, SMEM_BYTES, stream>>>(x,
        b_df1, b_df2, b_cm1, W_cm2, b_cm2,
        Am, Cm, Em, Fm, sa, sb,
        Wf1, Wf2, Wfc, Wfe, heagg, xan, out);
    sake_post<<<NN, 64, 0, stream>>>(h,
        W_pn1, b_pn1, W_pn2, b_pn2, W_nm1, b_nm1, W_nm2, b_nm2,
        heagg, xan, out);
}

// Round 9
// 159.446 us; speedup vs baseline: 1.0207x; 1.0207x over previous
//
#include <hip/hip_runtime.h>
#include <math.h>

#define NN 512
#define FF 64
#define HH 64
#define CC 32
#define KK 50

typedef unsigned int uint;
typedef short bhalf8_t __attribute__((ext_vector_type(8)));
typedef float f32x4_t __attribute__((ext_vector_type(4)));
#define MFMA16 __builtin_amdgcn_mfma_f32_16x16x32_bf16

union FragA { bhalf8_t v; uint u[4]; short4 h[2]; };

__device__ __forceinline__ float frcp(float x){ return __builtin_amdgcn_rcpf(x); }
__device__ __forceinline__ float fsilu(float x){ return x * frcp(1.0f + __expf(-x)); }
__device__ __forceinline__ float ftanh(float x){ return 1.0f - 2.0f * frcp(__expf(2.0f*x) + 1.0f); }
__device__ __forceinline__ short f2bf(float f){            // RNE f32->bf16
    uint u = __float_as_uint(f);
    return (short)((u + 0x7FFFu + ((u >> 16) & 1u)) >> 16);
}
__device__ __forceinline__ uint pack2(float lo, float hi){
    return (uint)(unsigned short)f2bf(lo) | ((uint)(unsigned short)f2bf(hi) << 16);
}

__device__ __forceinline__ float bfly_max(float v){
    #pragma unroll
    for (int m = 1; m < 64; m <<= 1) v = fmaxf(v, __shfl_xor(v, m, 64));
    return v;
}
__device__ __forceinline__ float bfly_sum(float v){
    #pragma unroll
    for (int m = 1; m < 64; m <<= 1) v += __shfl_xor(v, m, 64);
    return v;
}
__device__ __forceinline__ float block_max8(float v, float* red, int lane, int wid){
    v = bfly_max(v);
    __syncthreads();
    if (lane == 0) red[wid] = v;
    __syncthreads();
    float m = red[0];
    #pragma unroll
    for (int k = 1; k < 8; ++k) m = fmaxf(m, red[k]);
    return m;
}
__device__ __forceinline__ float block_sum8(float v, float* red, int lane, int wid){
    v = bfly_sum(v);
    __syncthreads();
    if (lane == 0) red[wid] = v;
    __syncthreads();
    float s = red[0];
    #pragma unroll
    for (int k = 1; k < 8; ++k) s += red[k];
    return s;
}

// ---------------- kernel 1: per-node projections + weight fragments ----------------
extern "C" __global__ __launch_bounds__(128)
void sake_pre(const float* __restrict__ h,
              const float* __restrict__ W_df_in, const float* __restrict__ b_df_in,
              const float* __restrict__ W_ew,    const float* __restrict__ b_ew,
              const float* __restrict__ W_sa,
              const float* __restrict__ W_df1, const float* __restrict__ W_df2,
              const float* __restrict__ W_cm1,
              float* __restrict__ Am, float* __restrict__ Cm,
              float* __restrict__ Em, float* __restrict__ Fm,
              float* __restrict__ sa, float* __restrict__ sb,
              short* __restrict__ Wf1, short* __restrict__ Wf2,
              short* __restrict__ Wfc, short* __restrict__ Wfe)
{
    const int b = blockIdx.x;
    const int t = threadIdx.x;
    if (b < NN) {
        __shared__ float hrow[FF];
        if (t < FF) hrow[t] = h[b*FF + t];
        __syncthreads();
        if (t < 64) {
            if (t < KK) {
                float a_ = 0.f, c_ = b_df_in[t];
                #pragma unroll 8
                for (int f = 0; f < FF; ++f) {
                    a_ += hrow[f] * W_df_in[f*KK + t];
                    c_ += hrow[f] * W_df_in[(FF+f)*KK + t];
                }
                Am[b*64 + t] = a_;   // [j][k] fp32, k-padded
                Cm[b*64 + t] = c_;   // [i][k], bias folded
            } else {
                Am[b*64 + t] = 0.f;  // zero-pad k=50..63 (makes he0 pad exact 0)
                Cm[b*64 + t] = 0.f;
            }
        } else if (t < 96) {
            int cc = t - 64;
            float e = 0.f, ff2 = b_ew[cc];
            #pragma unroll 8
            for (int f = 0; f < FF; ++f) {
                e   += hrow[f] * W_ew[f*CC + cc];
                ff2 += hrow[f] * W_ew[(FF+f)*CC + cc];
            }
            Em[b*CC + cc] = e;       // [j][c]
            Fm[b*CC + cc] = ff2;     // [i][c], b_ew folded
        } else if (t == 96) {
            float v = 0.f;
            #pragma unroll 8
            for (int f = 0; f < FF; ++f) v += hrow[f] * W_sa[f];
            sa[b] = v;
        } else if (t == 97) {
            float v = 0.f;
            #pragma unroll 8
            for (int f = 0; f < FF; ++f) v += hrow[f] * W_sa[FF + f];
            sb[b] = v;
        }
    } else {
        // weight -> bf16 MFMA-B-fragment order: idx = ((nt*2+ks)*64 + lane)*8 + q
        // value = W[k = 32*ks + 8*(lane>>4) + q][n = 16*nt + (lane&15)]
        const int wb = b - NN;
        const int cnt = (wb == 3) ? 2048 : 4096;
        #pragma unroll 4
        for (int idx = t; idx < cnt; idx += 128) {
            int q  = idx & 7;
            int l  = (idx >> 3) & 63;
            int ks = (idx >> 9) & 1;
            int nt = idx >> 10;
            int k  = 32*ks + 8*(l >> 4) + q;
            int n  = 16*nt + (l & 15);
            float v;
            if (wb == 0)      v = (k < KK) ? W_df1[k*HH + n] : 0.f;  // [50][64], pad rows 0
            else if (wb == 1) v = W_df2[k*HH + n];                    // [64][64]
            else if (wb == 2) v = W_cm1[k*HH + n];                    // [64][64]
            else              v = W_ew[(128 + k)*CC + n];             // he-rows of [192][32]
            short* dst = (wb == 0) ? Wf1 : (wb == 1) ? Wf2 : (wb == 2) ? Wfc : Wfe;
            dst[idx] = f2bf(v);
        }
    }
}

// ---------------- kernel 2: fused per-row-i MFMA main + epilogue ----------------
// Round-6 structure (512 thr / 8 waves / 4 t-iters, LDS weights, VGPR 96,
// 2 blocks/CU, all 512 blocks co-resident) + sake_post fused into the tail:
// he_agg[i]/xan[i] are block-local products, so the per-node epilogue MLPs
// run on wave 0 (unroll-16 pipelined loads) with no extra launch. Rounds
// 5-7 showed a stable ~110us residual with 3 launches vs ~60us with 2 -->
// launch-slot overhead ~55us is the dominant cost now.
#define OFF_W1   0        // 4096 shorts (8192B)
#define OFF_W2   8192
#define OFF_WC   16384
#define OFF_WE   24576    // 2048 shorts (4096B)
#define OFF_TILE 28672    // 8 waves * 16*76 shorts = 19456B
#define OFF_DIST 48128    // 512 f32
#define OFF_DX   50176    // 512*3 f32
#define OFF_ATTW 56320    // 512 f32
#define OFF_CORD 58368    // 512 f32
#define OFF_SCM  60416    // 64 f32
#define OFF_SB1  60672
#define OFF_SB2  60928
#define OFF_SBC1 61184
#define OFF_WC2  61440
#define OFF_FM   61696    // 32 f32
#define OFF_BC2  61824
#define SMEM_BYTES 61952

extern "C" __global__ __launch_bounds__(512)
void sake_main(const float* __restrict__ h, const float* __restrict__ x,
               const float* __restrict__ b_df1, const float* __restrict__ b_df2,
               const float* __restrict__ b_cm1,
               const float* __restrict__ W_cm2, const float* __restrict__ b_cm2,
               const float* __restrict__ W_pn1, const float* __restrict__ b_pn1,
               const float* __restrict__ W_pn2, const float* __restrict__ b_pn2,
               const float* __restrict__ W_nm1, const float* __restrict__ b_nm1,
               const float* __restrict__ W_nm2, const float* __restrict__ b_nm2,
               const float* __restrict__ Am, const float* __restrict__ Cm,
               const float* __restrict__ Em, const float* __restrict__ Fm,
               const float* __restrict__ sa, const float* __restrict__ sb,
               const short* __restrict__ Wf1, const short* __restrict__ Wf2,
               const short* __restrict__ Wfc, const short* __restrict__ Wfe,
               float* __restrict__ out)
{
    extern __shared__ char smem[];
    short* sW1    = (short*)(smem + OFF_W1);
    short* sW2    = (short*)(smem + OFF_W2);
    short* sWc    = (short*)(smem + OFF_WC);
    short* sWe    = (short*)(smem + OFF_WE);
    float* dist_s = (float*)(smem + OFF_DIST);
    float* dx_s   = (float*)(smem + OFF_DX);
    float* attw_s = (float*)(smem + OFF_ATTW);
    float* cord_s = (float*)(smem + OFF_CORD);
    float* sCm    = (float*)(smem + OFF_SCM);
    float* sB1    = (float*)(smem + OFF_SB1);
    float* sB2    = (float*)(smem + OFF_SB2);
    float* sBc1   = (float*)(smem + OFF_SBC1);
    float* sWc2   = (float*)(smem + OFF_WC2);
    float* sFm    = (float*)(smem + OFF_FM);
    float* sBc2   = (float*)(smem + OFF_BC2);

    __shared__ float red[8];
    __shared__ float sAggH[8][64];
    __shared__ float sAccX[8][96];
    __shared__ float xatt_f[96];
    __shared__ float heagg_f[64];
    __shared__ float xan_s[32];
    __shared__ float pn1_s[64];
    __shared__ float nm1_s[64];
    __shared__ float node_in[192];

    const int i   = blockIdx.x;
    const int tid = threadIdx.x;

    // ---- stage weights / row-i constants into LDS ----
    ((uint4*)sW1)[tid] = ((const uint4*)Wf1)[tid];
    ((uint4*)sW2)[tid] = ((const uint4*)Wf2)[tid];
    ((uint4*)sWc)[tid] = ((const uint4*)Wfc)[tid];
    if (tid < 256) ((uint4*)sWe)[tid] = ((const uint4*)Wfe)[tid];
    if (tid < 64) {
        sCm[tid]  = Cm[i*64 + tid];
        sB1[tid]  = b_df1[tid];
        sB2[tid]  = b_df2[tid];
        sBc1[tid] = b_cm1[tid];
        sWc2[tid] = W_cm2[tid];
    }
    if (tid < 32) sFm[tid] = Fm[i*CC + tid];
    if (tid == 0) sBc2[0] = b_cm2[0];

    // ---- phase A: softmax normalizers (1 j per thread) ----
    const float xi0 = x[i*3+0], xi1 = x[i*3+1], xi2 = x[i*3+2];
    const float sbi = sb[i];
    const int lane = tid & 63, wid = tid >> 6;
    {
        const int j = tid;
        float d0 = x[j*3+0]-xi0, d1 = x[j*3+1]-xi1, d2c = x[j*3+2]-xi2;
        float d2 = d0*d0 + d1*d1 + d2c*d2c;
        float dj = sqrtf(d2 + 1e-14f);
        float sv = fsilu(sa[j] + sbi);
        dist_s[j] = dj;
        dx_s[j*3+0] = d0; dx_s[j*3+1] = d1; dx_s[j*3+2] = d2c;
        float dmax = block_max8(dj, red, lane, wid);
        float dsum = block_sum8(__expf(dj - dmax), red, lane, wid);
        float smax = block_max8(sv, red, lane, wid);
        float ssum = block_sum8(__expf(sv - smax), red, lane, wid);
        float p = __expf((dj - dmax) + (sv - smax)) * frcp(dsum * ssum);
        float pmax = block_max8(p, red, lane, wid);
        float te = __expf(p - pmax);
        float tsum = block_sum8(te, red, lane, wid);
        attw_s[j] = te * frcp(tsum);
    }
    __syncthreads();

    // ---- phase B: MFMA chain, 8 waves x 4 M-tiles of 16 j ----
    const int w = wid, l = lane, a = l & 15, g = l >> 4;
    const float gf = (float)(8 * g);
    short* myTile = (short*)(smem + OFF_TILE) + w * (16 * 76);
    const float4* Amv  = (const float4*)Am;
    const float4* sCmv = (const float4*)sCm;

    float b1n[4], b2n[4], bcn[4], wc2r[4];
    #pragma unroll
    for (int nt = 0; nt < 4; ++nt) {
        b1n[nt]  = sB1[16*nt + a];
        b2n[nt]  = sB2[16*nt + a];
        bcn[nt]  = sBc1[16*nt + a];
        wc2r[nt] = sWc2[16*nt + a];
    }
    float fmr0 = sFm[a], fmr1 = sFm[16 + a];
    const float bc2v = sBc2[0];

    float aggH[4] = {0.f, 0.f, 0.f, 0.f};
    float xAcc[6] = {0.f, 0.f, 0.f, 0.f, 0.f, 0.f};

    const float MUK  = 5.0f / 49.0f;
    const float RBFC = -14.4269504f;   // -10 * log2(e)

    #pragma unroll 1
    for (int t = 0; t < 4; ++t) {
        const int Mb   = w*64 + t*16;
        const int jrow = Mb + a;         // A-row this lane builds/reads
        const int jred = Mb + 4*g;       // D-row base (add r)
        const float dj = dist_s[jrow];

        // ---- build he0 A-fragments (k = 32s + 8g + q), pad exact-0 ----
        FragA a0, a1;
        #pragma unroll
        for (int s = 0; s < 2; ++s) {
            float4 amL = Amv[jrow*16 + s*8 + g*2];
            float4 amH = Amv[jrow*16 + s*8 + g*2 + 1];
            float4 cmL = sCmv[s*8 + g*2];
            float4 cmH = sCmv[s*8 + g*2 + 1];
            float vq[8];
            vq[0] = amL.x + cmL.x; vq[1] = amL.y + cmL.y;
            vq[2] = amL.z + cmL.z; vq[3] = amL.w + cmL.w;
            vq[4] = amH.x + cmH.x; vq[5] = amH.y + cmH.y;
            vq[6] = amH.z + cmH.z; vq[7] = amH.w + cmH.w;
            #pragma unroll
            for (int q = 0; q < 8; ++q) {
                float kf = gf + (float)(32*s + q);
                float dd = dj - kf * MUK;
                vq[q] *= exp2f(dd * dd * RBFC);
            }
            FragA* ap = s ? &a1 : &a0;
            ap->u[0] = pack2(vq[0], vq[1]);
            ap->u[1] = pack2(vq[2], vq[3]);
            ap->u[2] = pack2(vq[4], vq[5]);
            ap->u[3] = pack2(vq[6], vq[7]);
        }

        // ---- stage 1: he1 = silu(he0 @ W_df1 + b1) ----
        f32x4_t acc[4];
        #pragma unroll
        for (int nt = 0; nt < 4; ++nt) acc[nt] = (f32x4_t){b1n[nt], b1n[nt], b1n[nt], b1n[nt]};
        #pragma unroll
        for (int s = 0; s < 2; ++s) {
            bhalf8_t av = s ? a1.v : a0.v;
            #pragma unroll
            for (int nt = 0; nt < 4; ++nt) {
                bhalf8_t bv = *(const bhalf8_t*)&sW1[((nt*2 + s)*64 + l)*8];
                acc[nt] = MFMA16(av, bv, acc[nt], 0, 0, 0);
            }
        }
        #pragma unroll
        for (int nt = 0; nt < 4; ++nt) {
            #pragma unroll
            for (int r = 0; r < 4; ++r)
                myTile[(4*g + r)*76 + a + 16*nt] = f2bf(fsilu(acc[nt][r]));
        }

        // ---- stage 2: he = he1 @ W_df2 + b2 ----
        FragA h0, h1;
        h0.h[0] = *(const short4*)&myTile[a*76 + 8*g];
        h0.h[1] = *(const short4*)&myTile[a*76 + 8*g + 4];
        h1.h[0] = *(const short4*)&myTile[a*76 + 32 + 8*g];
        h1.h[1] = *(const short4*)&myTile[a*76 + 32 + 8*g + 4];
        #pragma unroll
        for (int nt = 0; nt < 4; ++nt) acc[nt] = (f32x4_t){b2n[nt], b2n[nt], b2n[nt], b2n[nt]};
        #pragma unroll
        for (int s = 0; s < 2; ++s) {
            bhalf8_t av = s ? h1.v : h0.v;
            #pragma unroll
            for (int nt = 0; nt < 4; ++nt) {
                bhalf8_t bv = *(const bhalf8_t*)&sW2[((nt*2 + s)*64 + l)*8];
                acc[nt] = MFMA16(av, bv, acc[nt], 0, 0, 0);
            }
        }
        // he_agg partial (total_att * he) straight from D regs
        float at0 = attw_s[jred+0], at1 = attw_s[jred+1],
              at2 = attw_s[jred+2], at3 = attw_s[jred+3];
        #pragma unroll
        for (int nt = 0; nt < 4; ++nt) {
            aggH[nt] += at0*acc[nt][0] + at1*acc[nt][1] + at2*acc[nt][2] + at3*acc[nt][3];
            #pragma unroll
            for (int r = 0; r < 4; ++r)
                myTile[(4*g + r)*76 + a + 16*nt] = f2bf(acc[nt][r]);   // he -> tile
        }

        // re-read he as A-fragments (shared by edge & cm1 stages)
        FragA e0, e1;
        e0.h[0] = *(const short4*)&myTile[a*76 + 8*g];
        e0.h[1] = *(const short4*)&myTile[a*76 + 8*g + 4];
        e1.h[0] = *(const short4*)&myTile[a*76 + 32 + 8*g];
        e1.h[1] = *(const short4*)&myTile[a*76 + 32 + 8*g + 4];

        // ---- edge: w_edge = tanh(E_j + F_i + he @ W_ew_he), fused x_att reduce ----
        f32x4_t ae[2];
        ae[0] = (f32x4_t){0.f,0.f,0.f,0.f};
        ae[1] = (f32x4_t){0.f,0.f,0.f,0.f};
        #pragma unroll
        for (int s = 0; s < 2; ++s) {
            bhalf8_t av = s ? e1.v : e0.v;
            #pragma unroll
            for (int nt = 0; nt < 2; ++nt) {
                bhalf8_t bv = *(const bhalf8_t*)&sWe[((nt*2 + s)*64 + l)*8];
                ae[nt] = MFMA16(av, bv, ae[nt], 0, 0, 0);
            }
        }
        float xd[4][3];
        #pragma unroll
        for (int r = 0; r < 4; ++r) {
            float dr = dist_s[jred + r];
            float iv = frcp(dr*dr + 1e-5f);
            xd[r][0] = dx_s[(jred+r)*3+0] * iv;
            xd[r][1] = dx_s[(jred+r)*3+1] * iv;
            xd[r][2] = dx_s[(jred+r)*3+2] * iv;
        }
        #pragma unroll
        for (int nt = 0; nt < 2; ++nt) {
            float fmv = nt ? fmr1 : fmr0;
            #pragma unroll
            for (int r = 0; r < 4; ++r) {
                float em = Em[(jred+r)*CC + a + 16*nt];
                float wv = ftanh(ae[nt][r] + em + fmv);
                xAcc[nt*3+0] += wv * xd[r][0];
                xAcc[nt*3+1] += wv * xd[r][1];
                xAcc[nt*3+2] += wv * xd[r][2];
            }
        }

        // ---- coord MLP: coordw = silu(he @ W_cm1 + bc1) @ W_cm2 + bc2 ----
        #pragma unroll
        for (int nt = 0; nt < 4; ++nt) acc[nt] = (f32x4_t){bcn[nt], bcn[nt], bcn[nt], bcn[nt]};
        #pragma unroll
        for (int s = 0; s < 2; ++s) {
            bhalf8_t av = s ? e1.v : e0.v;
            #pragma unroll
            for (int nt = 0; nt < 4; ++nt) {
                bhalf8_t bv = *(const bhalf8_t*)&sWc[((nt*2 + s)*64 + l)*8];
                acc[nt] = MFMA16(av, bv, acc[nt], 0, 0, 0);
            }
        }
        float cw[4] = {0.f, 0.f, 0.f, 0.f};
        #pragma unroll
        for (int nt = 0; nt < 4; ++nt) {
            #pragma unroll
            for (int r = 0; r < 4; ++r)
                cw[r] += fsilu(acc[nt][r]) * wc2r[nt];
        }
        #pragma unroll
        for (int m = 1; m < 16; m <<= 1) {
            #pragma unroll
            for (int r = 0; r < 4; ++r) cw[r] += __shfl_xor(cw[r], m, 64);
        }
        if (a == 0) {
            #pragma unroll
            for (int r = 0; r < 4; ++r) cord_s[jred + r] = cw[r] + bc2v;
        }
    }

    // ---- wave-level combine of j-reductions ----
    #pragma unroll
    for (int nt = 0; nt < 4; ++nt) {
        aggH[nt] += __shfl_xor(aggH[nt], 16, 64);
        aggH[nt] += __shfl_xor(aggH[nt], 32, 64);
    }
    #pragma unroll
    for (int q = 0; q < 6; ++q) {
        xAcc[q] += __shfl_xor(xAcc[q], 16, 64);
        xAcc[q] += __shfl_xor(xAcc[q], 32, 64);
    }
    if (l < 16) {
        #pragma unroll
        for (int nt = 0; nt < 4; ++nt) sAggH[w][l + 16*nt] = aggH[nt];
        #pragma unroll
        for (int d = 0; d < 3; ++d) {
            sAccX[w][l*3 + d]        = xAcc[d];
            sAccX[w][(l+16)*3 + d]   = xAcc[3 + d];
        }
    }
    __syncthreads();

    // ---- x_new = sum_j dx * coordw + x_i ----
    {
        float cwv = cord_s[tid];
        float X0 = block_sum8(dx_s[tid*3+0]*cwv, red, lane, wid);
        float X1 = block_sum8(dx_s[tid*3+1]*cwv, red, lane, wid);
        float X2 = block_sum8(dx_s[tid*3+2]*cwv, red, lane, wid);
        if (tid == 0) {
            out[NN*HH + i*3+0] = X0 + xi0;
            out[NN*HH + i*3+1] = X1 + xi1;
            out[NN*HH + i*3+2] = X2 + xi2;
        }
    }

    // ---- cross-wave combine (all waves alive) ----
    if (tid < 64) {
        float s = 0.f;
        #pragma unroll
        for (int ww = 0; ww < 8; ++ww) s += sAggH[ww][tid];
        heagg_f[tid] = s;
    }
    if (tid < 96) {
        float s = 0.f;
        #pragma unroll
        for (int ww = 0; ww < 8; ++ww) s += sAccX[ww][tid];
        xatt_f[tid] = s;
    }
    __syncthreads();   // last full-block barrier; waves 1..7 exit after this

    // ---- fused epilogue: wave 0 only, no barriers (intra-wave LDS ordering) ----
    if (wid == 0) {
        if (l < 32) {
            float aa = xatt_f[l*3+0], bb = xatt_f[l*3+1], cc = xatt_f[l*3+2];
            xan_s[l] = sqrtf(aa*aa + bb*bb + cc*cc + 1e-14f);
        }
        float acc = b_pn1[l];
        #pragma unroll 8
        for (int c = 0; c < CC; ++c) acc += xan_s[c] * W_pn1[c*HH + l];
        pn1_s[l] = fsilu(acc);

        acc = b_pn2[l];
        #pragma unroll 16
        for (int k = 0; k < HH; ++k) acc += pn1_s[k] * W_pn2[k*HH + l];
        node_in[128 + l] = acc;              // norm_emb
        node_in[l]       = h[i*FF + l];      // h
        node_in[64 + l]  = heagg_f[l];       // he_agg

        acc = b_nm1[l];
        #pragma unroll 16
        for (int k = 0; k < 192; ++k) acc += node_in[k] * W_nm1[k*HH + l];
        nm1_s[l] = fsilu(acc);

        acc = b_nm2[l];
        #pragma unroll 16
        for (int k = 0; k < HH; ++k) acc += nm1_s[k] * W_nm2[k*HH + l];
        out[i*HH + l] = acc;                 // h_new
    }
}

extern "C" void kernel_launch(void* const* d_in, const int* in_sizes, int n_in,
                              void* d_out, int out_size, void* d_ws, size_t ws_size,
                              hipStream_t stream)
{
    const float* h       = (const float*)d_in[0];
    const float* x       = (const float*)d_in[1];
    const float* W_df_in = (const float*)d_in[2];
    const float* b_df_in = (const float*)d_in[3];
    const float* W_df1   = (const float*)d_in[4];
    const float* b_df1   = (const float*)d_in[5];
    const float* W_df2   = (const float*)d_in[6];
    const float* b_df2   = (const float*)d_in[7];
    const float* W_ew    = (const float*)d_in[8];
    const float* b_ew    = (const float*)d_in[9];
    const float* W_pn1   = (const float*)d_in[10];
    const float* b_pn1   = (const float*)d_in[11];
    const float* W_pn2   = (const float*)d_in[12];
    const float* b_pn2   = (const float*)d_in[13];
    const float* W_nm1   = (const float*)d_in[14];
    const float* b_nm1   = (const float*)d_in[15];
    const float* W_nm2   = (const float*)d_in[16];
    const float* b_nm2   = (const float*)d_in[17];
    const float* W_cm1   = (const float*)d_in[18];
    const float* b_cm1   = (const float*)d_in[19];
    const float* W_cm2   = (const float*)d_in[20];
    const float* b_cm2   = (const float*)d_in[21];
    const float* W_sa    = (const float*)d_in[22];
    float* out = (float*)d_out;

    float* ws = (float*)d_ws;
    float* Am = ws;                   // 512*64
    float* Cm = Am + 512*64;          // 512*64
    float* Em = Cm + 512*64;          // 512*32
    float* Fm = Em + 512*32;          // 512*32
    float* sa = Fm + 512*32;          // 512
    float* sb = sa + 512;             // 512
    short* Wf1 = (short*)(sb + 512);  // 4096 shorts
    short* Wf2 = Wf1 + 4096;
    short* Wfc = Wf2 + 4096;
    short* Wfe = Wfc + 4096;          // 2048 shorts

    (void)hipFuncSetAttribute((const void*)sake_main,
        hipFuncAttributeMaxDynamicSharedMemorySize, SMEM_BYTES);

    sake_pre<<<NN + 4, 128, 0, stream>>>(h, W_df_in, b_df_in, W_ew, b_ew, W_sa,
                                         W_df1, W_df2, W_cm1,
                                         Am, Cm, Em, Fm, sa, sb,
                                         Wf1, Wf2, Wfc, Wfe);
    sake_main<<<NN, 512, SMEM_BYTES, stream>>>(h, x,
        b_df1, b_df2, b_cm1, W_cm2, b_cm2,
        W_pn1, b_pn1, W_pn2, b_pn2, W_nm1, b_nm1, W_nm2, b_nm2,
        Am, Cm, Em, Fm, sa, sb,
        Wf1, Wf2, Wfc, Wfe, out);
}

// Round 12
// 151.548 us; speedup vs baseline: 1.0738x; 1.0521x over previous
//
#include <hip/hip_runtime.h>
#include <math.h>

#define NN 512
#define FF 64
#define HH 64
#define CC 32
#define KK 50

typedef unsigned int uint;
typedef short bhalf8_t __attribute__((ext_vector_type(8)));
typedef float f32x4_t __attribute__((ext_vector_type(4)));
#define MFMA16 __builtin_amdgcn_mfma_f32_16x16x32_bf16

union FragA { bhalf8_t v; uint u[4]; short4 h[2]; };

__device__ __forceinline__ float frcp(float x){ return __builtin_amdgcn_rcpf(x); }
__device__ __forceinline__ float fsilu(float x){ return x * frcp(1.0f + __expf(-x)); }
__device__ __forceinline__ float ftanh(float x){ return 1.0f - 2.0f * frcp(__expf(2.0f*x) + 1.0f); }
__device__ __forceinline__ short f2bf(float f){            // RNE f32->bf16
    uint u = __float_as_uint(f);
    return (short)((u + 0x7FFFu + ((u >> 16) & 1u)) >> 16);
}
__device__ __forceinline__ uint pack2(float lo, float hi){
    return (uint)(unsigned short)f2bf(lo) | ((uint)(unsigned short)f2bf(hi) << 16);
}

__device__ __forceinline__ float bfly_sum(float v){
    #pragma unroll
    for (int m = 1; m < 64; m <<= 1) v += __shfl_xor(v, m, 64);
    return v;
}
__device__ __forceinline__ float block_sum8(float v, float* red, int lane, int wid){
    v = bfly_sum(v);
    __syncthreads();
    if (lane == 0) red[wid] = v;
    __syncthreads();
    float s = red[0];
    #pragma unroll
    for (int k = 1; k < 8; ++k) s += red[k];
    return s;
}

// ---------------- kernel 1: per-node projections + weight fragments ----------------
extern "C" __global__ __launch_bounds__(128)
void sake_pre(const float* __restrict__ h,
              const float* __restrict__ W_df_in, const float* __restrict__ b_df_in,
              const float* __restrict__ W_ew,    const float* __restrict__ b_ew,
              const float* __restrict__ W_sa,
              const float* __restrict__ W_df1, const float* __restrict__ W_df2,
              const float* __restrict__ W_cm1,
              float* __restrict__ Am, float* __restrict__ Cm,
              float* __restrict__ Em, float* __restrict__ Fm,
              float* __restrict__ sa, float* __restrict__ sb,
              short* __restrict__ Wf1, short* __restrict__ Wf2,
              short* __restrict__ Wfc, short* __restrict__ Wfe)
{
    const int b = blockIdx.x;
    const int t = threadIdx.x;
    if (b < NN) {
        __shared__ float hrow[FF];
        if (t < FF) hrow[t] = h[b*FF + t];
        __syncthreads();
        if (t < 64) {
            if (t < KK) {
                float a_ = 0.f, c_ = b_df_in[t];
                #pragma unroll 8
                for (int f = 0; f < FF; ++f) {
                    a_ += hrow[f] * W_df_in[f*KK + t];
                    c_ += hrow[f] * W_df_in[(FF+f)*KK + t];
                }
                Am[b*64 + t] = a_;   // [j][k] fp32, k-padded
                Cm[b*64 + t] = c_;   // [i][k], bias folded
            } else {
                Am[b*64 + t] = 0.f;  // zero-pad k=50..63 (makes he0 pad exact 0)
                Cm[b*64 + t] = 0.f;
            }
        } else if (t < 96) {
            int cc = t - 64;
            float e = 0.f, ff2 = b_ew[cc];
            #pragma unroll 8
            for (int f = 0; f < FF; ++f) {
                e   += hrow[f] * W_ew[f*CC + cc];
                ff2 += hrow[f] * W_ew[(FF+f)*CC + cc];
            }
            Em[b*CC + cc] = e;       // [j][c]
            Fm[b*CC + cc] = ff2;     // [i][c], b_ew folded
        } else if (t == 96) {
            float v = 0.f;
            #pragma unroll 8
            for (int f = 0; f < FF; ++f) v += hrow[f] * W_sa[f];
            sa[b] = v;
        } else if (t == 97) {
            float v = 0.f;
            #pragma unroll 8
            for (int f = 0; f < FF; ++f) v += hrow[f] * W_sa[FF + f];
            sb[b] = v;
        }
    } else {
        // weight -> bf16 MFMA-B-fragment order: idx = ((nt*2+ks)*64 + lane)*8 + q
        // value = W[k = 32*ks + 8*(lane>>4) + q][n = 16*nt + (lane&15)]
        const int wb = b - NN;
        const int cnt = (wb == 3) ? 2048 : 4096;
        #pragma unroll 4
        for (int idx = t; idx < cnt; idx += 128) {
            int q  = idx & 7;
            int l  = (idx >> 3) & 63;
            int ks = (idx >> 9) & 1;
            int nt = idx >> 10;
            int k  = 32*ks + 8*(l >> 4) + q;
            int n  = 16*nt + (l & 15);
            float v;
            if (wb == 0)      v = (k < KK) ? W_df1[k*HH + n] : 0.f;  // [50][64], pad rows 0
            else if (wb == 1) v = W_df2[k*HH + n];                    // [64][64]
            else if (wb == 2) v = W_cm1[k*HH + n];                    // [64][64]
            else              v = W_ew[(128 + k)*CC + n];             // he-rows of [192][32]
            short* dst = (wb == 0) ? Wf1 : (wb == 1) ? Wf2 : (wb == 2) ? Wfc : Wfe;
            dst[idx] = f2bf(v);
        }
    }
}

// ---------------- kernel 2: fused per-row-i MFMA main + parallel epilogue ----------------
// Round-9 lesson: wave0-serial epilogue cost ~12us; now each MLP layer splits
// k across the 8 waves (partials in sAggH, 64-thread reduce) -> ~1-2us.
// Softmax max-subtraction dropped (dist<=~9, silu<=~8, p in (0,1): fp32-exp
// safe; identical in exact arithmetic). x_new accumulated in registers and
// piggybacked on the existing xor-16/32 wave reduce (cord_s + 3 block_sum8
// deleted). Occupancy is VGPR-bound (96->4 waves/SIMD): LDS size irrelevant.
#define OFF_W1   0        // 4096 shorts (8192B)
#define OFF_W2   8192
#define OFF_WC   16384
#define OFF_WE   24576    // 2048 shorts (4096B)
#define OFF_TILE 28672    // 8 waves * 16*76 shorts = 19456B
#define OFF_DIST 48128    // 512 f32
#define OFF_DX   50176    // 512*3 f32
#define OFF_ATTW 56320    // 512 f32
#define OFF_SCM  58368    // 64 f32
#define OFF_SB1  58624
#define OFF_SB2  58880
#define OFF_SBC1 59136
#define OFF_WC2  59392
#define OFF_FM   59648    // 32 f32
#define OFF_BC2  59776
#define SMEM_BYTES 59904

extern "C" __global__ __launch_bounds__(512)
void sake_main(const float* __restrict__ h, const float* __restrict__ x,
               const float* __restrict__ b_df1, const float* __restrict__ b_df2,
               const float* __restrict__ b_cm1,
               const float* __restrict__ W_cm2, const float* __restrict__ b_cm2,
               const float* __restrict__ W_pn1, const float* __restrict__ b_pn1,
               const float* __restrict__ W_pn2, const float* __restrict__ b_pn2,
               const float* __restrict__ W_nm1, const float* __restrict__ b_nm1,
               const float* __restrict__ W_nm2, const float* __restrict__ b_nm2,
               const float* __restrict__ Am, const float* __restrict__ Cm,
               const float* __restrict__ Em, const float* __restrict__ Fm,
               const float* __restrict__ sa, const float* __restrict__ sb,
               const short* __restrict__ Wf1, const short* __restrict__ Wf2,
               const short* __restrict__ Wfc, const short* __restrict__ Wfe,
               float* __restrict__ out)
{
    extern __shared__ char smem[];
    short* sW1    = (short*)(smem + OFF_W1);
    short* sW2    = (short*)(smem + OFF_W2);
    short* sWc    = (short*)(smem + OFF_WC);
    short* sWe    = (short*)(smem + OFF_WE);
    float* dist_s = (float*)(smem + OFF_DIST);
    float* dx_s   = (float*)(smem + OFF_DX);
    float* attw_s = (float*)(smem + OFF_ATTW);
    float* sCm    = (float*)(smem + OFF_SCM);
    float* sB1    = (float*)(smem + OFF_SB1);
    float* sB2    = (float*)(smem + OFF_SB2);
    float* sBc1   = (float*)(smem + OFF_SBC1);
    float* sWc2   = (float*)(smem + OFF_WC2);
    float* sFm    = (float*)(smem + OFF_FM);
    float* sBc2   = (float*)(smem + OFF_BC2);

    __shared__ float red[8];
    __shared__ float sAggH[8][64];     // heagg partials, then epilogue k-partials
    __shared__ float sAccX[8][96];
    __shared__ float sAccN[8][3];
    __shared__ float xatt_f[96];
    __shared__ float xan_s[32];
    __shared__ float pn1_s[64];
    __shared__ float nm1_s[64];
    __shared__ float node_in[192];

    const int i   = blockIdx.x;
    const int tid = threadIdx.x;

    // ---- stage weights / row-i constants into LDS ----
    ((uint4*)sW1)[tid] = ((const uint4*)Wf1)[tid];
    ((uint4*)sW2)[tid] = ((const uint4*)Wf2)[tid];
    ((uint4*)sWc)[tid] = ((const uint4*)Wfc)[tid];
    if (tid < 256) ((uint4*)sWe)[tid] = ((const uint4*)Wfe)[tid];
    if (tid < 64) {
        sCm[tid]  = Cm[i*64 + tid];
        sB1[tid]  = b_df1[tid];
        sB2[tid]  = b_df2[tid];
        sBc1[tid] = b_cm1[tid];
        sWc2[tid] = W_cm2[tid];
    }
    if (tid < 32) sFm[tid] = Fm[i*CC + tid];
    if (tid == 0) sBc2[0] = b_cm2[0];

    // ---- phase A: softmax normalizers, no max-subtraction (values bounded) ----
    const float xi0 = x[i*3+0], xi1 = x[i*3+1], xi2 = x[i*3+2];
    const float sbi = sb[i];
    const int lane = tid & 63, wid = tid >> 6;
    {
        const int j = tid;
        float d0 = x[j*3+0]-xi0, d1 = x[j*3+1]-xi1, d2c = x[j*3+2]-xi2;
        float d2 = d0*d0 + d1*d1 + d2c*d2c;
        float dj = sqrtf(d2 + 1e-14f);
        float sv = fsilu(sa[j] + sbi);
        dist_s[j] = dj;
        dx_s[j*3+0] = d0; dx_s[j*3+1] = d1; dx_s[j*3+2] = d2c;
        float dsum = block_sum8(__expf(dj), red, lane, wid);
        float ssum = block_sum8(__expf(sv), red, lane, wid);
        float p = __expf(dj + sv) * frcp(dsum * ssum);   // spa*sem, in (0,1)
        float te = __expf(p);
        float tsum = block_sum8(te, red, lane, wid);
        attw_s[j] = te * frcp(tsum);
    }
    __syncthreads();

    // ---- phase B: MFMA chain, 8 waves x 4 M-tiles of 16 j ----
    const int w = wid, l = lane, a = l & 15, g = l >> 4;
    const float gf = (float)(8 * g);
    short* myTile = (short*)(smem + OFF_TILE) + w * (16 * 76);
    const float4* Amv  = (const float4*)Am;
    const float4* sCmv = (const float4*)sCm;

    float b1n[4], b2n[4], bcn[4], wc2r[4];
    #pragma unroll
    for (int nt = 0; nt < 4; ++nt) {
        b1n[nt]  = sB1[16*nt + a];
        b2n[nt]  = sB2[16*nt + a];
        bcn[nt]  = sBc1[16*nt + a];
        wc2r[nt] = sWc2[16*nt + a];
    }
    float fmr0 = sFm[a], fmr1 = sFm[16 + a];
    const float bc2v = sBc2[0];

    float aggH[4] = {0.f, 0.f, 0.f, 0.f};
    float xAcc[6] = {0.f, 0.f, 0.f, 0.f, 0.f, 0.f};
    float xN[3]   = {0.f, 0.f, 0.f};

    const float MUK  = 5.0f / 49.0f;
    const float RBFC = -14.4269504f;   // -10 * log2(e)

    #pragma unroll 1
    for (int t = 0; t < 4; ++t) {
        const int Mb   = w*64 + t*16;
        const int jrow = Mb + a;         // A-row this lane builds/reads
        const int jred = Mb + 4*g;       // D-row base (add r)
        const float dj = dist_s[jrow];

        // ---- build he0 A-fragments (k = 32s + 8g + q), pad exact-0 ----
        FragA a0, a1;
        #pragma unroll
        for (int s = 0; s < 2; ++s) {
            float4 amL = Amv[jrow*16 + s*8 + g*2];
            float4 amH = Amv[jrow*16 + s*8 + g*2 + 1];
            float4 cmL = sCmv[s*8 + g*2];
            float4 cmH = sCmv[s*8 + g*2 + 1];
            float vq[8];
            vq[0] = amL.x + cmL.x; vq[1] = amL.y + cmL.y;
            vq[2] = amL.z + cmL.z; vq[3] = amL.w + cmL.w;
            vq[4] = amH.x + cmH.x; vq[5] = amH.y + cmH.y;
            vq[6] = amH.z + cmH.z; vq[7] = amH.w + cmH.w;
            #pragma unroll
            for (int q = 0; q < 8; ++q) {
                float kf = gf + (float)(32*s + q);
                float dd = dj - kf * MUK;
                vq[q] *= exp2f(dd * dd * RBFC);
            }
            FragA* ap = s ? &a1 : &a0;
            ap->u[0] = pack2(vq[0], vq[1]);
            ap->u[1] = pack2(vq[2], vq[3]);
            ap->u[2] = pack2(vq[4], vq[5]);
            ap->u[3] = pack2(vq[6], vq[7]);
        }

        // ---- stage 1: he1 = silu(he0 @ W_df1 + b1) ----
        f32x4_t acc[4];
        #pragma unroll
        for (int nt = 0; nt < 4; ++nt) acc[nt] = (f32x4_t){b1n[nt], b1n[nt], b1n[nt], b1n[nt]};
        #pragma unroll
        for (int s = 0; s < 2; ++s) {
            bhalf8_t av = s ? a1.v : a0.v;
            #pragma unroll
            for (int nt = 0; nt < 4; ++nt) {
                bhalf8_t bv = *(const bhalf8_t*)&sW1[((nt*2 + s)*64 + l)*8];
                acc[nt] = MFMA16(av, bv, acc[nt], 0, 0, 0);
            }
        }
        #pragma unroll
        for (int nt = 0; nt < 4; ++nt) {
            #pragma unroll
            for (int r = 0; r < 4; ++r)
                myTile[(4*g + r)*76 + a + 16*nt] = f2bf(fsilu(acc[nt][r]));
        }

        // ---- stage 2: he = he1 @ W_df2 + b2 ----
        FragA h0, h1;
        h0.h[0] = *(const short4*)&myTile[a*76 + 8*g];
        h0.h[1] = *(const short4*)&myTile[a*76 + 8*g + 4];
        h1.h[0] = *(const short4*)&myTile[a*76 + 32 + 8*g];
        h1.h[1] = *(const short4*)&myTile[a*76 + 32 + 8*g + 4];
        #pragma unroll
        for (int nt = 0; nt < 4; ++nt) acc[nt] = (f32x4_t){b2n[nt], b2n[nt], b2n[nt], b2n[nt]};
        #pragma unroll
        for (int s = 0; s < 2; ++s) {
            bhalf8_t av = s ? h1.v : h0.v;
            #pragma unroll
            for (int nt = 0; nt < 4; ++nt) {
                bhalf8_t bv = *(const bhalf8_t*)&sW2[((nt*2 + s)*64 + l)*8];
                acc[nt] = MFMA16(av, bv, acc[nt], 0, 0, 0);
            }
        }
        // he_agg partial (total_att * he) straight from D regs
        float at0 = attw_s[jred+0], at1 = attw_s[jred+1],
              at2 = attw_s[jred+2], at3 = attw_s[jred+3];
        #pragma unroll
        for (int nt = 0; nt < 4; ++nt) {
            aggH[nt] += at0*acc[nt][0] + at1*acc[nt][1] + at2*acc[nt][2] + at3*acc[nt][3];
            #pragma unroll
            for (int r = 0; r < 4; ++r)
                myTile[(4*g + r)*76 + a + 16*nt] = f2bf(acc[nt][r]);   // he -> tile
        }

        // re-read he as A-fragments (shared by edge & cm1 stages)
        FragA e0, e1;
        e0.h[0] = *(const short4*)&myTile[a*76 + 8*g];
        e0.h[1] = *(const short4*)&myTile[a*76 + 8*g + 4];
        e1.h[0] = *(const short4*)&myTile[a*76 + 32 + 8*g];
        e1.h[1] = *(const short4*)&myTile[a*76 + 32 + 8*g + 4];

        // ---- edge: w_edge = tanh(E_j + F_i + he @ W_ew_he), fused x_att reduce ----
        f32x4_t ae[2];
        ae[0] = (f32x4_t){0.f,0.f,0.f,0.f};
        ae[1] = (f32x4_t){0.f,0.f,0.f,0.f};
        #pragma unroll
        for (int s = 0; s < 2; ++s) {
            bhalf8_t av = s ? e1.v : e0.v;
            #pragma unroll
            for (int nt = 0; nt < 2; ++nt) {
                bhalf8_t bv = *(const bhalf8_t*)&sWe[((nt*2 + s)*64 + l)*8];
                ae[nt] = MFMA16(av, bv, ae[nt], 0, 0, 0);
            }
        }
        float dxr[4][3], xd[4][3];
        #pragma unroll
        for (int r = 0; r < 4; ++r) {
            float dr = dist_s[jred + r];
            float iv = frcp(dr*dr + 1e-5f);
            #pragma unroll
            for (int d = 0; d < 3; ++d) {
                dxr[r][d] = dx_s[(jred+r)*3+d];
                xd[r][d]  = dxr[r][d] * iv;
            }
        }
        #pragma unroll
        for (int nt = 0; nt < 2; ++nt) {
            float fmv = nt ? fmr1 : fmr0;
            #pragma unroll
            for (int r = 0; r < 4; ++r) {
                float em = Em[(jred+r)*CC + a + 16*nt];
                float wv = ftanh(ae[nt][r] + em + fmv);
                xAcc[nt*3+0] += wv * xd[r][0];
                xAcc[nt*3+1] += wv * xd[r][1];
                xAcc[nt*3+2] += wv * xd[r][2];
            }
        }

        // ---- coord MLP: coordw = silu(he @ W_cm1 + bc1) @ W_cm2 + bc2 ----
        #pragma unroll
        for (int nt = 0; nt < 4; ++nt) acc[nt] = (f32x4_t){bcn[nt], bcn[nt], bcn[nt], bcn[nt]};
        #pragma unroll
        for (int s = 0; s < 2; ++s) {
            bhalf8_t av = s ? e1.v : e0.v;
            #pragma unroll
            for (int nt = 0; nt < 4; ++nt) {
                bhalf8_t bv = *(const bhalf8_t*)&sWc[((nt*2 + s)*64 + l)*8];
                acc[nt] = MFMA16(av, bv, acc[nt], 0, 0, 0);
            }
        }
        float cw[4] = {0.f, 0.f, 0.f, 0.f};
        #pragma unroll
        for (int nt = 0; nt < 4; ++nt) {
            #pragma unroll
            for (int r = 0; r < 4; ++r)
                cw[r] += fsilu(acc[nt][r]) * wc2r[nt];
        }
        #pragma unroll
        for (int m = 1; m < 16; m <<= 1) {
            #pragma unroll
            for (int r = 0; r < 4; ++r) cw[r] += __shfl_xor(cw[r], m, 64);
        }
        // x_new partial: all 16 a-lanes hold identical cw/dxr -> accumulate in regs
        #pragma unroll
        for (int r = 0; r < 4; ++r) {
            float cwf = cw[r] + bc2v;
            xN[0] += cwf * dxr[r][0];
            xN[1] += cwf * dxr[r][1];
            xN[2] += cwf * dxr[r][2];
        }
    }

    // ---- wave-level combine of j-reductions ----
    #pragma unroll
    for (int nt = 0; nt < 4; ++nt) {
        aggH[nt] += __shfl_xor(aggH[nt], 16, 64);
        aggH[nt] += __shfl_xor(aggH[nt], 32, 64);
    }
    #pragma unroll
    for (int q = 0; q < 6; ++q) {
        xAcc[q] += __shfl_xor(xAcc[q], 16, 64);
        xAcc[q] += __shfl_xor(xAcc[q], 32, 64);
    }
    #pragma unroll
    for (int d = 0; d < 3; ++d) {   // sums 4 distinct g-groups (a-lanes identical)
        xN[d] += __shfl_xor(xN[d], 16, 64);
        xN[d] += __shfl_xor(xN[d], 32, 64);
    }
    if (l < 16) {
        #pragma unroll
        for (int nt = 0; nt < 4; ++nt) sAggH[w][l + 16*nt] = aggH[nt];
        #pragma unroll
        for (int d = 0; d < 3; ++d) {
            sAccX[w][l*3 + d]        = xAcc[d];
            sAccX[w][(l+16)*3 + d]   = xAcc[3 + d];
        }
    }
    if (l == 0) {
        sAccN[w][0] = xN[0]; sAccN[w][1] = xN[1]; sAccN[w][2] = xN[2];
    }
    __syncthreads();

    // ---- cross-wave combine (parallel thread ranges) ----
    if (tid < 64) {
        float s = 0.f;
        #pragma unroll
        for (int ww = 0; ww < 8; ++ww) s += sAggH[ww][tid];
        node_in[64 + tid] = s;             // he_agg
        node_in[tid]      = h[i*FF + tid]; // h
    } else if (tid >= 128 && tid < 224) {
        int q = tid - 128;
        float s = 0.f;
        #pragma unroll
        for (int ww = 0; ww < 8; ++ww) s += sAccX[ww][q];
        xatt_f[q] = s;
    } else if (tid >= 224 && tid < 227) {
        int d = tid - 224;
        float s = 0.f;
        #pragma unroll
        for (int ww = 0; ww < 8; ++ww) s += sAccN[ww][d];
        out[NN*HH + i*3 + d] = s + ((d == 0) ? xi0 : (d == 1) ? xi1 : xi2);
    }
    __syncthreads();
    if (tid < 32) {
        float aa = xatt_f[tid*3+0], bb = xatt_f[tid*3+1], cc = xatt_f[tid*3+2];
        xan_s[tid] = sqrtf(aa*aa + bb*bb + cc*cc + 1e-14f);
    }
    __syncthreads();

    // ---- parallel epilogue: each layer k-split across 8 waves ----
    const int en = tid & 63, ekg = tid >> 6;
    {   // pn1: 64 out x 32 k (4 k per kg)
        float p = 0.f;
        #pragma unroll
        for (int r = 0; r < 4; ++r) { int k = ekg*4 + r; p += xan_s[k] * W_pn1[k*HH + en]; }
        sAggH[ekg][en] = p;
    }
    __syncthreads();
    if (tid < 64) {
        float s = b_pn1[tid];
        #pragma unroll
        for (int kg = 0; kg < 8; ++kg) s += sAggH[kg][tid];
        pn1_s[tid] = fsilu(s);
    }
    __syncthreads();
    {   // pn2: 64 x 64 (8 k per kg)
        float p = 0.f;
        #pragma unroll
        for (int r = 0; r < 8; ++r) { int k = ekg*8 + r; p += pn1_s[k] * W_pn2[k*HH + en]; }
        sAggH[ekg][en] = p;
    }
    __syncthreads();
    if (tid < 64) {
        float s = b_pn2[tid];
        #pragma unroll
        for (int kg = 0; kg < 8; ++kg) s += sAggH[kg][tid];
        node_in[128 + tid] = s;            // norm_emb
    }
    __syncthreads();
    {   // nm1: 64 x 192 (24 k per kg)
        float p = 0.f;
        #pragma unroll
        for (int r = 0; r < 24; ++r) { int k = ekg*24 + r; p += node_in[k] * W_nm1[k*HH + en]; }
        sAggH[ekg][en] = p;
    }
    __syncthreads();
    if (tid < 64) {
        float s = b_nm1[tid];
        #pragma unroll
        for (int kg = 0; kg < 8; ++kg) s += sAggH[kg][tid];
        nm1_s[tid] = fsilu(s);
    }
    __syncthreads();
    {   // nm2: 64 x 64 (8 k per kg)
        float p = 0.f;
        #pragma unroll
        for (int r = 0; r < 8; ++r) { int k = ekg*8 + r; p += nm1_s[k] * W_nm2[k*HH + en]; }
        sAggH[ekg][en] = p;
    }
    __syncthreads();
    if (tid < 64) {
        float s = b_nm2[tid];
        #pragma unroll
        for (int kg = 0; kg < 8; ++kg) s += sAggH[kg][tid];
        out[i*HH + tid] = s;               // h_new
    }
}

extern "C" void kernel_launch(void* const* d_in, const int* in_sizes, int n_in,
                              void* d_out, int out_size, void* d_ws, size_t ws_size,
                              hipStream_t stream)
{
    const float* h       = (const float*)d_in[0];
    const float* x       = (const float*)d_in[1];
    const float* W_df_in = (const float*)d_in[2];
    const float* b_df_in = (const float*)d_in[3];
    const float* W_df1   = (const float*)d_in[4];
    const float* b_df1   = (const float*)d_in[5];
    const float* W_df2   = (const float*)d_in[6];
    const float* b_df2   = (const float*)d_in[7];
    const float* W_ew    = (const float*)d_in[8];
    const float* b_ew    = (const float*)d_in[9];
    const float* W_pn1   = (const float*)d_in[10];
    const float* b_pn1   = (const float*)d_in[11];
    const float* W_pn2   = (const float*)d_in[12];
    const float* b_pn2   = (const float*)d_in[13];
    const float* W_nm1   = (const float*)d_in[14];
    const float* b_nm1   = (const float*)d_in[15];
    const float* W_nm2   = (const float*)d_in[16];
    const float* b_nm2   = (const float*)d_in[17];
    const float* W_cm1   = (const float*)d_in[18];
    const float* b_cm1   = (const float*)d_in[19];
    const float* W_cm2   = (const float*)d_in[20];
    const float* b_cm2   = (const float*)d_in[21];
    const float* W_sa    = (const float*)d_in[22];
    float* out = (float*)d_out;

    float* ws = (float*)d_ws;
    float* Am = ws;                   // 512*64
    float* Cm = Am + 512*64;          // 512*64
    float* Em = Cm + 512*64;          // 512*32
    float* Fm = Em + 512*32;          // 512*32
    float* sa = Fm + 512*32;          // 512
    float* sb = sa + 512;             // 512
    short* Wf1 = (short*)(sb + 512);  // 4096 shorts
    short* Wf2 = Wf1 + 4096;
    short* Wfc = Wf2 + 4096;
    short* Wfe = Wfc + 4096;          // 2048 shorts

    (void)hipFuncSetAttribute((const void*)sake_main,
        hipFuncAttributeMaxDynamicSharedMemorySize, SMEM_BYTES);

    sake_pre<<<NN + 4, 128, 0, stream>>>(h, W_df_in, b_df_in, W_ew, b_ew, W_sa,
                                         W_df1, W_df2, W_cm1,
                                         Am, Cm, Em, Fm, sa, sb,
                                         Wf1, Wf2, Wfc, Wfe);
    sake_main<<<NN, 512, SMEM_BYTES, stream>>>(h, x,
        b_df1, b_df2, b_cm1, W_cm2, b_cm2,
        W_pn1, b_pn1, W_pn2, b_pn2, W_nm1, b_nm1, W_nm2, b_nm2,
        Am, Cm, Em, Fm, sa, sb,
        Wf1, Wf2, Wfc, Wfe, out);
}